// Round 12
// baseline (2018.086 us; speedup 1.0000x reference)
//
#include <hip/hip_runtime.h>
#include <cstdint>
#include <cstddef>

typedef __bf16 bf16;
typedef __attribute__((ext_vector_type(8))) __bf16 bf16x8;
typedef __attribute__((ext_vector_type(4))) float f32x4;

constexpr int kV = 32000, kE = 1024, kL = 6, kH = 16, kB = 4, kT = 1024;
constexpr int kHS = 64, kFF = 4096;
constexpr int kM = kB * kT;              // 4096 token rows
constexpr float kQScale = 0.0451038961f; // (1/32) * log2(e)  -> use exp2f

typedef __attribute__((address_space(1))) void gv_t;
typedef __attribute__((address_space(3))) void lv_t;

__device__ inline void gload_lds16(const void* g, void* l) {
  __builtin_amdgcn_global_load_lds((gv_t*)g, (lv_t*)l, 16, 0, 0);
}

#define SB0() __builtin_amdgcn_sched_barrier(0)
#define LGK0() asm volatile("s_waitcnt lgkmcnt(0)" ::: "memory")

enum { EPI_BF16 = 0, EPI_BF16_BIAS_RELU = 1, EPI_F32 = 2, EPI_F32_RES = 3, EPI_F32_BIAS = 4 };

__device__ inline void xcd_swz(int& bx, int& by) {
  int gx = gridDim.x, gy = gridDim.y;
  int nxy = gx * gy;
  int orig = by * gx + bx;
  int q = nxy >> 3, r = nxy & 7, xcd = orig & 7, idx = orig >> 3;
  int logical = (xcd < r ? xcd * (q + 1) : r * (q + 1) + (xcd - r) * q) + idx;
  bx = logical / gy;
  by = logical % gy;
}

// ================= 256x256 4-slice ring GEMM (verified R8) — LM head only =================
template <int EPI>
__global__ __launch_bounds__(512, 2) void gemm256_k(
    const bf16* __restrict__ Ag, const bf16* __restrict__ Bg, void* Cg,
    const float* __restrict__ bias, const float* __restrict__ resid,
    int K, long lda, long ldb, long ldc) {
  extern __shared__ bf16 lds[];
  constexpr int SL = 8192;
  bf16* As = lds;
  bf16* Bs = lds + 4 * SL;

  const int tid = threadIdx.x, lane = tid & 63, w = tid >> 6;
  int bx = blockIdx.x, by = blockIdx.y;
  xcd_swz(bx, by);
  const long tm = (long)by * 256, tn = (long)bx * 256;
  const int wr = w >> 2, wc = w & 3;
  const int lr = lane & 15, kg = lane >> 4;

  const int p0 = tid, p1 = 512 + tid;
  const int r0 = p0 >> 2, ls0 = (p0 & 3) ^ ((r0 >> 1) & 3);
  const int r1 = p1 >> 2, ls1 = (p1 & 3) ^ ((r1 >> 1) & 3);
  const bf16* a0 = Ag + (tm + r0) * lda + ls0 * 8;
  const bf16* a1 = Ag + (tm + r1) * lda + ls1 * 8;
  const bf16* b0 = Bg + (tn + r0) * ldb + ls0 * 8;
  const bf16* b1 = Bg + (tn + r1) * ldb + ls1 * 8;
  const int wb = w * 1024;

  auto stage = [&](int s) {
    const int slot = s & 3;
    const long k0 = (long)s * 32;
    char* Ab = (char*)As + slot * (SL * 2);
    char* Bb = (char*)Bs + slot * (SL * 2);
    gload_lds16(a0 + k0, Ab + wb);
    gload_lds16(a1 + k0, Ab + 8192 + wb);
    gload_lds16(b0 + k0, Bb + wb);
    gload_lds16(b1 + k0, Bb + 8192 + wb);
  };

  int aoff[8], boff[4];
#pragma unroll
  for (int mi = 0; mi < 8; mi++) {
    int ar = wr * 128 + mi * 16 + lr;
    aoff[mi] = ar * 64 + ((kg ^ ((ar >> 1) & 3)) << 4);
  }
#pragma unroll
  for (int ni = 0; ni < 4; ni++) {
    int br = wc * 64 + ni * 16 + lr;
    boff[ni] = br * 64 + ((kg ^ ((br >> 1) & 3)) << 4);
  }

  f32x4 acc[8][4] = {};
  stage(0);
  stage(1);
  stage(2);
  const int NS = K >> 5;
  for (int s = 0; s < NS; s++) {
    SB0();
    if (s <= NS - 3)
      asm volatile("s_waitcnt vmcnt(8)" ::: "memory");
    else if (s == NS - 2)
      asm volatile("s_waitcnt vmcnt(4)" ::: "memory");
    else
      asm volatile("s_waitcnt vmcnt(0)" ::: "memory");
    __builtin_amdgcn_s_barrier();
    SB0();
    if (s + 3 < NS) stage(s + 3);
    const char* Ab = (const char*)As + (s & 3) * (SL * 2);
    const char* Bb = (const char*)Bs + (s & 3) * (SL * 2);
    bf16x8 af[8], bfr[4];
#pragma unroll
    for (int mi = 0; mi < 8; mi++) af[mi] = *(const bf16x8*)(Ab + aoff[mi]);
#pragma unroll
    for (int ni = 0; ni < 4; ni++) bfr[ni] = *(const bf16x8*)(Bb + boff[ni]);
    __builtin_amdgcn_s_setprio(1);
#pragma unroll
    for (int mi = 0; mi < 8; mi++)
#pragma unroll
      for (int ni = 0; ni < 4; ni++)
        acc[mi][ni] =
            __builtin_amdgcn_mfma_f32_16x16x32_bf16(af[mi], bfr[ni], acc[mi][ni], 0, 0, 0);
    __builtin_amdgcn_s_setprio(0);
  }

#pragma unroll
  for (int mi = 0; mi < 8; mi++) {
#pragma unroll
    for (int ni = 0; ni < 4; ni++) {
      const long rr = tm + wr * 128 + mi * 16 + kg * 4;
      const long cc = tn + wc * 64 + ni * 16 + lr;
      float bi = 0.f;
      if constexpr (EPI == EPI_BF16_BIAS_RELU || EPI == EPI_F32_BIAS) bi = bias[cc];
      if constexpr (EPI == EPI_F32_RES) bi = bias ? bias[cc] : 0.f;
#pragma unroll
      for (int j = 0; j < 4; j++) {
        long off = (rr + j) * ldc + cc;
        float val = acc[mi][ni][j];
        if constexpr (EPI == EPI_BF16)
          ((bf16*)Cg)[off] = (bf16)val;
        else if constexpr (EPI == EPI_BF16_BIAS_RELU)
          ((bf16*)Cg)[off] = (bf16)fmaxf(val + bi, 0.f);
        else if constexpr (EPI == EPI_F32)
          ((float*)Cg)[off] = val;
        else if constexpr (EPI == EPI_F32_RES)
          ((float*)Cg)[off] = resid[off] + val + bi;
        else
          ((float*)Cg)[off] = val + bi;
      }
    }
  }
}

// ================= 3-slot ring GEMM, high-occupancy (BM x BN, 4 waves) =================
// Same counted-vmcnt ring discipline as gemm256 (proven): wait leaves exactly one
// slot in flight; stage(s+2) after barrier reuses the slot read in iter s-1
// (separated by barrier(s)). 3 slots -> 48/36 KB LDS -> 3+ blocks/CU: co-resident
// blocks overlap each other's barrier stalls (m114/m97 mechanism).
template <int BM, int BN, int EPI>
__global__ __launch_bounds__(256, 3) void ring3_k(
    const bf16* __restrict__ Ag, const bf16* __restrict__ Bg, void* Cg,
    const float* __restrict__ bias, const float* __restrict__ resid,
    int K, long lda, long ldb, long ldc) {
  extern __shared__ bf16 lds[];
  char* Lb = (char*)lds;
  constexpr int A_IT = BM * 4 / 256;  // A gloads per thread per slot
  constexpr int B_IT = BN * 4 / 256;
  constexpr int L = A_IT + B_IT;      // loads/thread/slot (vmcnt unit)
  constexpr int SLOT = (BM + BN) * 64;  // bytes per slot
  constexpr int NWN = BN / 64, NWM = 4 / NWN, WM = BM / NWM;
  constexpr int MI = WM / 16;

  const int tid = threadIdx.x, lane = tid & 63, w = tid >> 6;
  int bx = blockIdx.x, by = blockIdx.y;
  xcd_swz(bx, by);
  const long tm = (long)by * BM, tn = (long)bx * BN;
  const int wr = w / NWN, wc = w % NWN;
  const int wm0 = wr * WM, wn0 = wc * 64;
  const int lr = lane & 15, kg = lane >> 4;

  const bf16* aSrc[A_IT];
  const bf16* bSrc[B_IT];
#pragma unroll
  for (int i = 0; i < A_IT; i++) {
    int p = i * 256 + tid;
    int row = p >> 2, g = (p & 3) ^ ((row >> 1) & 3);
    aSrc[i] = Ag + (tm + row) * lda + g * 8;
  }
#pragma unroll
  for (int i = 0; i < B_IT; i++) {
    int p = i * 256 + tid;
    int row = p >> 2, g = (p & 3) ^ ((row >> 1) & 3);
    bSrc[i] = Bg + (tn + row) * ldb + g * 8;
  }
  const int wdst = (tid & ~63) * 16;

  auto stage = [&](int s) {
    char* Ab = Lb + (s % 3) * SLOT;
    char* Bb = Ab + BM * 64;
    const long k0 = (long)s * 32;
#pragma unroll
    for (int i = 0; i < A_IT; i++) gload_lds16(aSrc[i] + k0, Ab + i * 4096 + wdst);
#pragma unroll
    for (int i = 0; i < B_IT; i++) gload_lds16(bSrc[i] + k0, Bb + i * 4096 + wdst);
  };

  int aoff[MI], boff[4];
#pragma unroll
  for (int mi = 0; mi < MI; mi++) {
    int ar = wm0 + mi * 16 + lr;
    aoff[mi] = ar * 64 + ((kg ^ ((ar >> 1) & 3)) << 4);
  }
#pragma unroll
  for (int ni = 0; ni < 4; ni++) {
    int br = wn0 + ni * 16 + lr;
    boff[ni] = BM * 64 + br * 64 + ((kg ^ ((br >> 1) & 3)) << 4);
  }

  f32x4 acc[MI][4] = {};
  stage(0);
  stage(1);
  const int NS = K >> 5;
  for (int s = 0; s < NS; s++) {
    SB0();
    if (s + 1 < NS) {
      if constexpr (L == 4)
        asm volatile("s_waitcnt vmcnt(4)" ::: "memory");
      else
        asm volatile("s_waitcnt vmcnt(3)" ::: "memory");
    } else {
      asm volatile("s_waitcnt vmcnt(0)" ::: "memory");
    }
    __builtin_amdgcn_s_barrier();
    SB0();
    if (s + 2 < NS) stage(s + 2);
    const char* Sb = Lb + (s % 3) * SLOT;
    bf16x8 af[MI], bfr[4];
#pragma unroll
    for (int mi = 0; mi < MI; mi++) af[mi] = *(const bf16x8*)(Sb + aoff[mi]);
#pragma unroll
    for (int ni = 0; ni < 4; ni++) bfr[ni] = *(const bf16x8*)(Sb + boff[ni]);
    __builtin_amdgcn_s_setprio(1);
#pragma unroll
    for (int mi = 0; mi < MI; mi++)
#pragma unroll
      for (int ni = 0; ni < 4; ni++)
        acc[mi][ni] =
            __builtin_amdgcn_mfma_f32_16x16x32_bf16(af[mi], bfr[ni], acc[mi][ni], 0, 0, 0);
    __builtin_amdgcn_s_setprio(0);
  }

#pragma unroll
  for (int mi = 0; mi < MI; mi++) {
#pragma unroll
    for (int ni = 0; ni < 4; ni++) {
      const long rr = tm + wm0 + mi * 16 + kg * 4;
      const long cc = tn + wn0 + ni * 16 + lr;
      float bi = 0.f;
      if constexpr (EPI == EPI_BF16_BIAS_RELU || EPI == EPI_F32_BIAS) bi = bias[cc];
      if constexpr (EPI == EPI_F32_RES) bi = bias ? bias[cc] : 0.f;
#pragma unroll
      for (int j = 0; j < 4; j++) {
        long off = (rr + j) * ldc + cc;
        float val = acc[mi][ni][j];
        if constexpr (EPI == EPI_BF16)
          ((bf16*)Cg)[off] = (bf16)val;
        else if constexpr (EPI == EPI_BF16_BIAS_RELU)
          ((bf16*)Cg)[off] = (bf16)fmaxf(val + bi, 0.f);
        else if constexpr (EPI == EPI_F32)
          ((float*)Cg)[off] = val;
        else if constexpr (EPI == EPI_F32_RES)
          ((float*)Cg)[off] = resid[off] + val + bi;
        else
          ((float*)Cg)[off] = val + bi;
      }
    }
  }
}

// ================= fused flash attention v2 (exp2 variant) =================
__global__ __launch_bounds__(128) void fa_k(const bf16* __restrict__ qkv,
                                            const bf16* __restrict__ vtG,
                                            bf16* __restrict__ out) {
  extern __shared__ bf16 lds[];
  char* L = (char*)lds;
  const int tid = threadIdx.x, lane = tid & 63, wq = tid >> 6;
  const int lr = lane & 15, kg = lane >> 4;
  const int bh = blockIdx.x, z = blockIdx.y;
  const int b = bh >> 4, hh = bh & 15;
  const long bq = (long)b * kT;
  const int qt = z < 4 ? z : 11 - z;
  const int q0 = qt * 128;
  const bf16* qbase = qkv + (bq + q0) * 3072 + hh * 64;
  const bf16* vbase = vtG + (long)bh * 64 * kT;

#pragma unroll
  for (int i = 0; i < 8; i++) {
    int p = i * 128 + tid;
    int row = p >> 3, s = p & 7;
    gload_lds16(qbase + (long)row * 3072 + ((s ^ (row & 7)) * 8),
                L + (i * 128 + (tid & ~63)) * 16);
  }
  auto stageKV = [&](int buf, int t) {
    const bf16* kb = qkv + (bq + t * 64) * 3072 + 1024 + hh * 64;
    const bf16* vb = vbase + t * 64;
#pragma unroll
    for (int i = 0; i < 4; i++) {
      int p = i * 128 + tid;
      int key = p >> 3, s = p & 7;
      gload_lds16(kb + (long)key * 3072 + ((s ^ (key & 7)) * 8),
                  L + 16384 + buf * 8192 + (i * 128 + (tid & ~63)) * 16);
    }
#pragma unroll
    for (int i = 0; i < 4; i++) {
      int p = i * 128 + tid;
      int key = p >> 3, s = p & 7;
      gload_lds16(vb + (long)key * kT + s * 8,
                  L + 32768 + buf * 8192 + (i * 128 + (tid & ~63)) * 16);
    }
  };
  stageKV(0, 0);
  __syncthreads();

  // Q fragments pre-scaled by (1/32)*log2(e)  (softmax via exp2)
  bf16x8 qf[4][2];
#pragma unroll
  for (int qi = 0; qi < 4; qi++)
#pragma unroll
    for (int ks = 0; ks < 2; ks++) {
      int qr = wq * 64 + qi * 16 + lr;
      bf16x8 v = *(const bf16x8*)(L + qr * 128 + ((ks * 64 + kg * 16) ^ ((qr & 7) << 4)));
#pragma unroll
      for (int e = 0; e < 8; e++) v[e] = (bf16)((float)v[e] * kQScale);
      qf[qi][ks] = v;
    }

  f32x4 O[4][4] = {};
  float lrun[4] = {0.f, 0.f, 0.f, 0.f};
  char* Pw = L + 49152 + wq * 9216;

  const int nt = 2 * qt + 2;
  int cur = 0;
  for (int t = 0; t < nt; t++) {
    if (t + 1 < nt) stageKV(cur ^ 1, t + 1);

    const char* Kb = L + 16384 + cur * 8192;
    f32x4 S[4][4] = {};
#pragma unroll
    for (int ks = 0; ks < 2; ks++) {
      bf16x8 kf[4];
#pragma unroll
      for (int ki = 0; ki < 4; ki++) {
        int key = ki * 16 + lr;
        kf[ki] = *(const bf16x8*)(Kb + key * 128 + ((ks * 64 + kg * 16) ^ ((key & 7) << 4)));
      }
#pragma unroll
      for (int ki = 0; ki < 4; ki++)
#pragma unroll
        for (int qi = 0; qi < 4; qi++)
          S[ki][qi] =
              __builtin_amdgcn_mfma_f32_16x16x32_bf16(kf[ki], qf[qi][ks], S[ki][qi], 0, 0, 0);
    }

    const int kvb = t * 64;
#pragma unroll
    for (int qi = 0; qi < 4; qi++) {
      const int q = q0 + wq * 64 + qi * 16 + lr;
      float ls = 0.f;
#pragma unroll
      for (int ki = 0; ki < 4; ki++) {
        union { bf16 h[4]; uint2 u; } pk;
#pragma unroll
        for (int j = 0; j < 4; j++) {
          int kv = kvb + ki * 16 + kg * 4 + j;
          float e = (kv <= q) ? exp2f(S[ki][qi][j]) : 0.f;
          ls += e;
          pk.h[j] = (bf16)e;
        }
        *(uint2*)(Pw + (qi * 16 + lr) * 144 + (ki * 16 + kg * 4) * 2) = pk.u;
      }
      ls += __shfl_xor(ls, 16);
      ls += __shfl_xor(ls, 32);
      lrun[qi] += ls;
    }
    LGK0();
    SB0();

    const char* Vb = L + 32768 + cur * 8192;
#pragma unroll
    for (int ks = 0; ks < 2; ks++) {
      bf16x8 pf[4], vf[4];
#pragma unroll
      for (int qi = 0; qi < 4; qi++)
        pf[qi] = *(const bf16x8*)(Pw + (qi * 16 + lr) * 144 + ks * 64 + kg * 16);
#pragma unroll
      for (int di = 0; di < 4; di++) {
        int d = di * 16 + lr;
        vf[di] = *(const bf16x8*)(Vb + d * 128 + ((ks * 64 + kg * 16) ^ ((d & 7) << 4)));
      }
#pragma unroll
      for (int qi = 0; qi < 4; qi++)
#pragma unroll
        for (int di = 0; di < 4; di++)
          O[qi][di] =
              __builtin_amdgcn_mfma_f32_16x16x32_bf16(pf[qi], vf[di], O[qi][di], 0, 0, 0);
    }
    __syncthreads();
    cur ^= 1;
  }

#pragma unroll
  for (int qi = 0; qi < 4; qi++) {
#pragma unroll
    for (int j = 0; j < 4; j++) {
      float lv = __shfl(lrun[qi], kg * 4 + j);
      float inv = 1.f / lv;
      long grow = bq + q0 + wq * 64 + qi * 16 + kg * 4 + j;
#pragma unroll
      for (int di = 0; di < 4; di++)
        out[grow * kE + hh * 64 + di * 16 + lr] = (bf16)(O[qi][di][j] * inv);
    }
  }
}

// ---------------- V section of qkv [M,3E] -> vtG [B*H][64 d][1024 t], pre-swizzled
__global__ void vtrans_k(const bf16* __restrict__ qkv, bf16* __restrict__ vt) {
  __shared__ bf16 tbuf[32][33];
  int z = blockIdx.z;
  int b = z >> 4, h = z & 15;
  int t0 = blockIdx.x * 32, s0 = blockIdx.y * 32;
  int tx = threadIdx.x, ty = threadIdx.y;
#pragma unroll
  for (int i = 0; i < 32; i += 8)
    tbuf[ty + i][tx] = qkv[((long)b * kT + t0 + ty + i) * 3072 + 2048 + h * 64 + s0 + tx];
  __syncthreads();
#pragma unroll
  for (int i = 0; i < 32; i += 8) {
    int d = s0 + ty + i;
    int tt = t0 + tx;
    int g = (tt >> 3) & 7, e = tt & 7;
    long idx = ((long)z * 64 + d) * kT + (tt & ~63) + ((g ^ (d & 7)) << 3) + e;
    vt[idx] = tbuf[tx][ty + i];
  }
}

// ---------------- transpose + f32->bf16 convert (vectorized writes)
__global__ void tcvt_k(const float* __restrict__ in, bf16* __restrict__ out, int K, int N,
                       long in_zs, long out_zs) {
  __shared__ float t[64][33];
  long z = blockIdx.z;
  in += z * in_zs;
  out += z * out_zs;
  int n0 = blockIdx.x * 32, k0 = blockIdx.y * 64;
  int tid = threadIdx.y * 32 + threadIdx.x;
  int tx = threadIdx.x, ty = threadIdx.y;
#pragma unroll
  for (int i = 0; i < 8; i++) t[ty + i * 8][tx] = in[(long)(k0 + ty + i * 8) * N + n0 + tx];
  __syncthreads();
#pragma unroll
  for (int it = 0; it < 2; it++) {
    int q = it * 256 + tid;
    int r = q >> 4;
    int jj = q & 15;
    union { bf16 h[4]; uint2 u; } pk;
#pragma unroll
    for (int e = 0; e < 4; e++) pk.h[e] = (bf16)t[jj * 4 + e][r];
    *(uint2*)(out + (long)(n0 + r) * K + k0 + jj * 4) = pk.u;
  }
}

// ---------------- embedding
__global__ void embed_k(const int* __restrict__ toks, const float* __restrict__ te,
                        const float* __restrict__ pe, float* __restrict__ x) {
  int row = blockIdx.x, tid = threadIdx.x;
  int t = row & (kT - 1);
  long tok = toks[row];
  float4 a = ((const float4*)(te + tok * kE))[tid];
  float4 p = ((const float4*)(pe + (long)t * kE))[tid];
  float4 r{a.x + p.x, a.y + p.y, a.z + p.z, a.w + p.w};
  ((float4*)(x + (long)row * kE))[tid] = r;
}

// ---------------- LayerNorm (f32 in) -> bf16 out
__global__ void ln_k(const float* __restrict__ x, const float* __restrict__ g,
                     const float* __restrict__ b, bf16* __restrict__ h) {
  int row = blockIdx.x, tid = threadIdx.x, lane = tid & 63, w = tid >> 6;
  const float4 v = ((const float4*)(x + (long)row * kE))[tid];
  float s = v.x + v.y + v.z + v.w;
  float ss = v.x * v.x + v.y * v.y + v.z * v.z + v.w * v.w;
#pragma unroll
  for (int o = 32; o; o >>= 1) {
    s += __shfl_xor(s, o);
    ss += __shfl_xor(ss, o);
  }
  __shared__ float r1[4], r2[4];
  if (lane == 0) { r1[w] = s; r2[w] = ss; }
  __syncthreads();
  s = r1[0] + r1[1] + r1[2] + r1[3];
  ss = r2[0] + r2[1] + r2[2] + r2[3];
  float mean = s * (1.f / kE);
  float var = ss * (1.f / kE) - mean * mean;
  float rs = rsqrtf(var + 1e-5f);
  float4 gg = ((const float4*)g)[tid];
  float4 bb = ((const float4*)b)[tid];
  union { bf16 o[4]; uint2 u; } pk;
  pk.o[0] = (bf16)((v.x - mean) * rs * gg.x + bb.x);
  pk.o[1] = (bf16)((v.y - mean) * rs * gg.y + bb.y);
  pk.o[2] = (bf16)((v.z - mean) * rs * gg.z + bb.z);
  pk.o[3] = (bf16)((v.w - mean) * rs * gg.w + bb.w);
  ((uint2*)(h + (long)row * kE))[tid] = pk.u;
}

// ---------------- f32 -> bf16 cast
__global__ void cast_k(const float* __restrict__ x, bf16* __restrict__ o) {
  long i = (long)blockIdx.x * 256 + threadIdx.x;
  float4 v = ((const float4*)x)[i];
  union { bf16 b[4]; uint2 u; } pk;
  pk.b[0] = (bf16)v.x;
  pk.b[1] = (bf16)v.y;
  pk.b[2] = (bf16)v.z;
  pk.b[3] = (bf16)v.w;
  ((uint2*)o)[i] = pk.u;
}

extern "C" void kernel_launch(void* const* d_in, const int* in_sizes, int n_in,
                              void* d_out, int out_size, void* d_ws, size_t ws_size,
                              hipStream_t stream) {
  const int* toks = (const int*)d_in[0];
  const float* te = (const float*)d_in[1];
  const float* pe = (const float*)d_in[2];
  const float* Wq = (const float*)d_in[3];
  const float* Wk = (const float*)d_in[4];
  const float* Wv = (const float*)d_in[5];
  const float* Wo = (const float*)d_in[6];
  const float* g1 = (const float*)d_in[7];
  const float* be1 = (const float*)d_in[8];
  const float* W1 = (const float*)d_in[9];
  const float* bb1 = (const float*)d_in[10];
  const float* W2 = (const float*)d_in[11];
  const float* bb2 = (const float*)d_in[12];
  const float* g2 = (const float*)d_in[13];
  const float* be2 = (const float*)d_in[14];
  const float* lmw = (const float*)d_in[15];
  const float* lmb = (const float*)d_in[16];

  hipFuncSetAttribute(reinterpret_cast<const void*>(&gemm256_k<EPI_F32_BIAS>),
                      hipFuncAttributeMaxDynamicSharedMemorySize, 131072);
  hipFuncSetAttribute(reinterpret_cast<const void*>(&ring3_k<128, 128, EPI_BF16>),
                      hipFuncAttributeMaxDynamicSharedMemorySize, 49152);
  hipFuncSetAttribute(reinterpret_cast<const void*>(&ring3_k<128, 128, EPI_BF16_BIAS_RELU>),
                      hipFuncAttributeMaxDynamicSharedMemorySize, 49152);
  hipFuncSetAttribute(reinterpret_cast<const void*>(&ring3_k<128, 64, EPI_F32_RES>),
                      hipFuncAttributeMaxDynamicSharedMemorySize, 36864);
  hipFuncSetAttribute(reinterpret_cast<const void*>(&fa_k),
                      hipFuncAttributeMaxDynamicSharedMemorySize, 67584);

  char* ws = (char*)d_ws;
  size_t off = 0;
  auto alloc = [&](size_t bytes) -> char* {
    char* p = ws + off;
    off += (bytes + 255) & ~(size_t)255;
    return p;
  };
  bf16* WqkvT = (bf16*)alloc((size_t)kL * 3 * kE * kE * 2);
  bf16* WoT = (bf16*)alloc((size_t)kL * kE * kE * 2);
  bf16* W1T = (bf16*)alloc((size_t)kL * kE * kFF * 2);
  bf16* W2T = (bf16*)alloc((size_t)kL * kE * kFF * 2);
  bf16* lmT = (bf16*)alloc((size_t)kV * kE * 2);
  float* x = (float*)alloc((size_t)kM * kE * 4);
  bf16* h = (bf16*)alloc((size_t)kM * kE * 2);
  bf16* qkv = (bf16*)alloc((size_t)kM * 3 * kE * 2);
  bf16* at = (bf16*)alloc((size_t)kM * kE * 2);
  bf16* vtG = (bf16*)alloc((size_t)kB * kH * 64 * kT * 2);

  bf16* mid = (bf16*)d_out;  // scratch; LM head overwrites d_out at the end

  const long EE = (long)kE * kE;
  dim3 tb(32, 8);
  tcvt_k<<<dim3(kE / 32, kE / 64, kL), tb, 0, stream>>>(Wq, WqkvT, kE, kE, EE, 3 * EE);
  tcvt_k<<<dim3(kE / 32, kE / 64, kL), tb, 0, stream>>>(Wk, WqkvT + EE, kE, kE, EE, 3 * EE);
  tcvt_k<<<dim3(kE / 32, kE / 64, kL), tb, 0, stream>>>(Wv, WqkvT + 2 * EE, kE, kE, EE, 3 * EE);
  tcvt_k<<<dim3(kE / 32, kE / 64, kL), tb, 0, stream>>>(Wo, WoT, kE, kE, EE, EE);
  tcvt_k<<<dim3(kFF / 32, kE / 64, kL), tb, 0, stream>>>(W1, W1T, kE, kFF, 4 * EE, 4 * EE);
  tcvt_k<<<dim3(kE / 32, kFF / 64, kL), tb, 0, stream>>>(W2, W2T, kFF, kE, 4 * EE, 4 * EE);
  tcvt_k<<<dim3(kV / 32, kE / 64, 1), tb, 0, stream>>>(lmw, lmT, kE, kV, 0, 0);

  embed_k<<<kM, 256, 0, stream>>>(toks, te, pe, x);

  for (int l = 0; l < kL; l++) {
    ln_k<<<kM, 256, 0, stream>>>(x, g1 + l * kE, be1 + l * kE, h);
    // qkv = h @ [Wq|Wk|Wv]   (768 blocks, 3/CU)
    ring3_k<128, 128, EPI_BF16><<<dim3(3 * kE / 128, kM / 128), 256, 49152, stream>>>(
        h, WqkvT + (size_t)l * 3 * EE, qkv, nullptr, nullptr, kE, kE, kE, 3 * kE);
    vtrans_k<<<dim3(kT / 32, kHS / 32, kB * kH), tb, 0, stream>>>(qkv, vtG);
    fa_k<<<dim3(kB * kH, 8), 128, 67584, stream>>>(qkv, vtG, at);
    // x += at @ Wo   (512 blocks)
    ring3_k<128, 64, EPI_F32_RES><<<dim3(kE / 64, kM / 128), 256, 36864, stream>>>(
        at, WoT + (size_t)l * EE, x, nullptr, x, kE, kE, kE, kE);
    ln_k<<<kM, 256, 0, stream>>>(x, g2 + l * kE, be2 + l * kE, h);
    // mid = relu(h @ W1 + b1)   (1024 blocks)
    ring3_k<128, 128, EPI_BF16_BIAS_RELU><<<dim3(kFF / 128, kM / 128), 256, 49152, stream>>>(
        h, W1T + (size_t)l * (size_t)kFF * kE, mid, bb1 + l * kFF, nullptr, kE, kE, kE, kFF);
    // x += mid @ W2 + b2   (512 blocks, K=4096)
    ring3_k<128, 64, EPI_F32_RES><<<dim3(kE / 64, kM / 128), 256, 36864, stream>>>(
        mid, W2T + (size_t)l * (size_t)kE * kFF, x, bb2 + l * kE, x, kFF, kFF, kFF, kE);
  }
  cast_k<<<kM * kE / 1024, 256, 0, stream>>>(x, h);
  gemm256_k<EPI_F32_BIAS><<<dim3(kV / 256, kM / 256), 512, 131072, stream>>>(
      h, lmT, d_out, lmb, nullptr, kE, kE, kE, kV);
}

// Round 13
// 2016.642 us; speedup vs baseline: 1.0007x; 1.0007x over previous
//
#include <hip/hip_runtime.h>
#include <cstdint>
#include <cstddef>

typedef __bf16 bf16;
typedef __attribute__((ext_vector_type(8))) __bf16 bf16x8;
typedef __attribute__((ext_vector_type(4))) float f32x4;

constexpr int kV = 32000, kE = 1024, kL = 6, kH = 16, kB = 4, kT = 1024;
constexpr int kHS = 64, kFF = 4096;
constexpr int kM = kB * kT;              // 4096 token rows
constexpr float kQScale = 0.0451038961f; // (1/32) * log2(e)  -> exp2f softmax

typedef __attribute__((address_space(1))) void gv_t;
typedef __attribute__((address_space(3))) void lv_t;

__device__ inline void gload_lds16(const void* g, void* l) {
  __builtin_amdgcn_global_load_lds((gv_t*)g, (lv_t*)l, 16, 0, 0);
}

#define SB0() __builtin_amdgcn_sched_barrier(0)
#define LGK0() asm volatile("s_waitcnt lgkmcnt(0)" ::: "memory")

enum { EPI_BF16 = 0, EPI_BF16_BIAS_RELU = 1, EPI_F32 = 2, EPI_F32_RES = 3, EPI_F32_BIAS = 4 };

__device__ inline void xcd_swz(int& bx, int& by) {
  int gx = gridDim.x, gy = gridDim.y;
  int nxy = gx * gy;
  int orig = by * gx + bx;
  int q = nxy >> 3, r = nxy & 7, xcd = orig & 7, idx = orig >> 3;
  int logical = (xcd < r ? xcd * (q + 1) : r * (q + 1) + (xcd - r) * q) + idx;
  bx = logical / gy;
  by = logical % gy;
}

// ================= 256x256 4-slice ring GEMM (verified R8) =================
template <int EPI>
__global__ __launch_bounds__(512, 2) void gemm256_k(
    const bf16* __restrict__ Ag, const bf16* __restrict__ Bg, void* Cg,
    const float* __restrict__ bias, const float* __restrict__ resid,
    int K, long lda, long ldb, long ldc) {
  extern __shared__ bf16 lds[];
  constexpr int SL = 8192;
  bf16* As = lds;
  bf16* Bs = lds + 4 * SL;

  const int tid = threadIdx.x, lane = tid & 63, w = tid >> 6;
  int bx = blockIdx.x, by = blockIdx.y;
  xcd_swz(bx, by);
  const long tm = (long)by * 256, tn = (long)bx * 256;
  const int wr = w >> 2, wc = w & 3;
  const int lr = lane & 15, kg = lane >> 4;

  const int p0 = tid, p1 = 512 + tid;
  const int r0 = p0 >> 2, ls0 = (p0 & 3) ^ ((r0 >> 1) & 3);
  const int r1 = p1 >> 2, ls1 = (p1 & 3) ^ ((r1 >> 1) & 3);
  const bf16* a0 = Ag + (tm + r0) * lda + ls0 * 8;
  const bf16* a1 = Ag + (tm + r1) * lda + ls1 * 8;
  const bf16* b0 = Bg + (tn + r0) * ldb + ls0 * 8;
  const bf16* b1 = Bg + (tn + r1) * ldb + ls1 * 8;
  const int wb = w * 1024;

  auto stage = [&](int s) {
    const int slot = s & 3;
    const long k0 = (long)s * 32;
    char* Ab = (char*)As + slot * (SL * 2);
    char* Bb = (char*)Bs + slot * (SL * 2);
    gload_lds16(a0 + k0, Ab + wb);
    gload_lds16(a1 + k0, Ab + 8192 + wb);
    gload_lds16(b0 + k0, Bb + wb);
    gload_lds16(b1 + k0, Bb + 8192 + wb);
  };

  int aoff[8], boff[4];
#pragma unroll
  for (int mi = 0; mi < 8; mi++) {
    int ar = wr * 128 + mi * 16 + lr;
    aoff[mi] = ar * 64 + ((kg ^ ((ar >> 1) & 3)) << 4);
  }
#pragma unroll
  for (int ni = 0; ni < 4; ni++) {
    int br = wc * 64 + ni * 16 + lr;
    boff[ni] = br * 64 + ((kg ^ ((br >> 1) & 3)) << 4);
  }

  f32x4 acc[8][4] = {};
  stage(0);
  stage(1);
  stage(2);
  const int NS = K >> 5;
  for (int s = 0; s < NS; s++) {
    SB0();
    if (s <= NS - 3)
      asm volatile("s_waitcnt vmcnt(8)" ::: "memory");
    else if (s == NS - 2)
      asm volatile("s_waitcnt vmcnt(4)" ::: "memory");
    else
      asm volatile("s_waitcnt vmcnt(0)" ::: "memory");
    __builtin_amdgcn_s_barrier();
    SB0();
    if (s + 3 < NS) stage(s + 3);
    const char* Ab = (const char*)As + (s & 3) * (SL * 2);
    const char* Bb = (const char*)Bs + (s & 3) * (SL * 2);
    bf16x8 af[8], bfr[4];
#pragma unroll
    for (int mi = 0; mi < 8; mi++) af[mi] = *(const bf16x8*)(Ab + aoff[mi]);
#pragma unroll
    for (int ni = 0; ni < 4; ni++) bfr[ni] = *(const bf16x8*)(Bb + boff[ni]);
    __builtin_amdgcn_s_setprio(1);
#pragma unroll
    for (int mi = 0; mi < 8; mi++)
#pragma unroll
      for (int ni = 0; ni < 4; ni++)
        acc[mi][ni] =
            __builtin_amdgcn_mfma_f32_16x16x32_bf16(af[mi], bfr[ni], acc[mi][ni], 0, 0, 0);
    __builtin_amdgcn_s_setprio(0);
  }

#pragma unroll
  for (int mi = 0; mi < 8; mi++) {
#pragma unroll
    for (int ni = 0; ni < 4; ni++) {
      const long rr = tm + wr * 128 + mi * 16 + kg * 4;
      const long cc = tn + wc * 64 + ni * 16 + lr;
      float bi = 0.f;
      if constexpr (EPI == EPI_BF16_BIAS_RELU || EPI == EPI_F32_BIAS) bi = bias[cc];
      if constexpr (EPI == EPI_F32_RES) bi = bias ? bias[cc] : 0.f;
#pragma unroll
      for (int j = 0; j < 4; j++) {
        long off = (rr + j) * ldc + cc;
        float val = acc[mi][ni][j];
        if constexpr (EPI == EPI_BF16)
          ((bf16*)Cg)[off] = (bf16)val;
        else if constexpr (EPI == EPI_BF16_BIAS_RELU)
          ((bf16*)Cg)[off] = (bf16)fmaxf(val + bi, 0.f);
        else if constexpr (EPI == EPI_F32)
          ((float*)Cg)[off] = val;
        else if constexpr (EPI == EPI_F32_RES)
          ((float*)Cg)[off] = resid[off] + val + bi;
        else
          ((float*)Cg)[off] = val + bi;
      }
    }
  }
}

// ================= 128x128 4-slice ring GEMM (verified R8) =================
template <int EPI>
__global__ __launch_bounds__(256, 2) void ring128_k(
    const bf16* __restrict__ Ag, const bf16* __restrict__ Bg, void* Cg,
    const float* __restrict__ bias, const float* __restrict__ resid,
    int K, long lda, long ldb, long ldc) {
  extern __shared__ bf16 lds[];
  char* Lb = (char*)lds;  // 4 slices x (A 8192B + B 8192B)
  const int tid = threadIdx.x, lane = tid & 63, w = tid >> 6;
  int bx = blockIdx.x, by = blockIdx.y;
  xcd_swz(bx, by);
  const long tm = (long)by * 128, tn = (long)bx * 128;
  const int wr = w >> 1, wc = w & 1;  // wave grid 2 x 2
  const int lr = lane & 15, kg = lane >> 4;

  const int r0 = tid >> 2, g0 = (tid & 3) ^ ((r0 >> 1) & 3);
  const int r1 = (256 + tid) >> 2, g1 = ((256 + tid) & 3) ^ ((r1 >> 1) & 3);
  const bf16* a0 = Ag + (tm + r0) * lda + g0 * 8;
  const bf16* a1 = Ag + (tm + r1) * lda + g1 * 8;
  const bf16* b0 = Bg + (tn + r0) * ldb + g0 * 8;
  const bf16* b1 = Bg + (tn + r1) * ldb + g1 * 8;
  const int wb = w * 1024;

  auto stage = [&](int s) {
    const int slot = s & 3;
    const long k0 = (long)s * 32;
    char* Ab = Lb + slot * 16384;
    char* Bb = Ab + 8192;
    gload_lds16(a0 + k0, Ab + wb);
    gload_lds16(a1 + k0, Ab + 4096 + wb);
    gload_lds16(b0 + k0, Bb + wb);
    gload_lds16(b1 + k0, Bb + 4096 + wb);
  };

  int aoff[4], boff[4];
#pragma unroll
  for (int mi = 0; mi < 4; mi++) {
    int ar = wr * 64 + mi * 16 + lr;
    aoff[mi] = ar * 64 + ((kg ^ ((ar >> 1) & 3)) << 4);
  }
#pragma unroll
  for (int ni = 0; ni < 4; ni++) {
    int br = wc * 64 + ni * 16 + lr;
    boff[ni] = br * 64 + ((kg ^ ((br >> 1) & 3)) << 4);
  }

  f32x4 acc[4][4] = {};
  stage(0);
  stage(1);
  stage(2);
  const int NS = K >> 5;
  for (int s = 0; s < NS; s++) {
    SB0();
    if (s <= NS - 3)
      asm volatile("s_waitcnt vmcnt(8)" ::: "memory");
    else if (s == NS - 2)
      asm volatile("s_waitcnt vmcnt(4)" ::: "memory");
    else
      asm volatile("s_waitcnt vmcnt(0)" ::: "memory");
    __builtin_amdgcn_s_barrier();
    SB0();
    if (s + 3 < NS) stage(s + 3);
    const char* Ab = Lb + (s & 3) * 16384;
    const char* Bb = Ab + 8192;
    bf16x8 af[4], bfr[4];
#pragma unroll
    for (int mi = 0; mi < 4; mi++) af[mi] = *(const bf16x8*)(Ab + aoff[mi]);
#pragma unroll
    for (int ni = 0; ni < 4; ni++) bfr[ni] = *(const bf16x8*)(Bb + boff[ni]);
    __builtin_amdgcn_s_setprio(1);
#pragma unroll
    for (int mi = 0; mi < 4; mi++)
#pragma unroll
      for (int ni = 0; ni < 4; ni++)
        acc[mi][ni] =
            __builtin_amdgcn_mfma_f32_16x16x32_bf16(af[mi], bfr[ni], acc[mi][ni], 0, 0, 0);
    __builtin_amdgcn_s_setprio(0);
  }

#pragma unroll
  for (int mi = 0; mi < 4; mi++) {
#pragma unroll
    for (int ni = 0; ni < 4; ni++) {
      const long rr = tm + wr * 64 + mi * 16 + kg * 4;
      const long cc = tn + wc * 64 + ni * 16 + lr;
      float bi = 0.f;
      if constexpr (EPI == EPI_BF16_BIAS_RELU || EPI == EPI_F32_BIAS) bi = bias[cc];
      if constexpr (EPI == EPI_F32_RES) bi = bias ? bias[cc] : 0.f;
#pragma unroll
      for (int j = 0; j < 4; j++) {
        long off = (rr + j) * ldc + cc;
        float val = acc[mi][ni][j];
        if constexpr (EPI == EPI_BF16)
          ((bf16*)Cg)[off] = (bf16)val;
        else if constexpr (EPI == EPI_BF16_BIAS_RELU)
          ((bf16*)Cg)[off] = (bf16)fmaxf(val + bi, 0.f);
        else if constexpr (EPI == EPI_F32)
          ((float*)Cg)[off] = val;
        else if constexpr (EPI == EPI_F32_RES)
          ((float*)Cg)[off] = resid[off] + val + bi;
        else
          ((float*)Cg)[off] = val + bi;
      }
    }
  }
}

// ================= fused flash attention v2 (exp2 variant) =================
__global__ __launch_bounds__(128) void fa_k(const bf16* __restrict__ qkv,
                                            const bf16* __restrict__ vtG,
                                            bf16* __restrict__ out) {
  extern __shared__ bf16 lds[];
  char* L = (char*)lds;
  const int tid = threadIdx.x, lane = tid & 63, wq = tid >> 6;
  const int lr = lane & 15, kg = lane >> 4;
  const int bh = blockIdx.x, z = blockIdx.y;
  const int b = bh >> 4, hh = bh & 15;
  const long bq = (long)b * kT;
  const int qt = z < 4 ? z : 11 - z;
  const int q0 = qt * 128;
  const bf16* qbase = qkv + (bq + q0) * 3072 + hh * 64;
  const bf16* vbase = vtG + (long)bh * 64 * kT;

#pragma unroll
  for (int i = 0; i < 8; i++) {
    int p = i * 128 + tid;
    int row = p >> 3, s = p & 7;
    gload_lds16(qbase + (long)row * 3072 + ((s ^ (row & 7)) * 8),
                L + (i * 128 + (tid & ~63)) * 16);
  }
  auto stageKV = [&](int buf, int t) {
    const bf16* kb = qkv + (bq + t * 64) * 3072 + 1024 + hh * 64;
    const bf16* vb = vbase + t * 64;
#pragma unroll
    for (int i = 0; i < 4; i++) {
      int p = i * 128 + tid;
      int key = p >> 3, s = p & 7;
      gload_lds16(kb + (long)key * 3072 + ((s ^ (key & 7)) * 8),
                  L + 16384 + buf * 8192 + (i * 128 + (tid & ~63)) * 16);
    }
#pragma unroll
    for (int i = 0; i < 4; i++) {
      int p = i * 128 + tid;
      int key = p >> 3, s = p & 7;
      gload_lds16(vb + (long)key * kT + s * 8,
                  L + 32768 + buf * 8192 + (i * 128 + (tid & ~63)) * 16);
    }
  };
  stageKV(0, 0);
  __syncthreads();

  // Q fragments pre-scaled by (1/32)*log2(e)
  bf16x8 qf[4][2];
#pragma unroll
  for (int qi = 0; qi < 4; qi++)
#pragma unroll
    for (int ks = 0; ks < 2; ks++) {
      int qr = wq * 64 + qi * 16 + lr;
      bf16x8 v = *(const bf16x8*)(L + qr * 128 + ((ks * 64 + kg * 16) ^ ((qr & 7) << 4)));
#pragma unroll
      for (int e = 0; e < 8; e++) v[e] = (bf16)((float)v[e] * kQScale);
      qf[qi][ks] = v;
    }

  f32x4 O[4][4] = {};
  float lrun[4] = {0.f, 0.f, 0.f, 0.f};
  char* Pw = L + 49152 + wq * 9216;

  const int nt = 2 * qt + 2;
  int cur = 0;
  for (int t = 0; t < nt; t++) {
    if (t + 1 < nt) stageKV(cur ^ 1, t + 1);

    const char* Kb = L + 16384 + cur * 8192;
    f32x4 S[4][4] = {};
#pragma unroll
    for (int ks = 0; ks < 2; ks++) {
      bf16x8 kf[4];
#pragma unroll
      for (int ki = 0; ki < 4; ki++) {
        int key = ki * 16 + lr;
        kf[ki] = *(const bf16x8*)(Kb + key * 128 + ((ks * 64 + kg * 16) ^ ((key & 7) << 4)));
      }
#pragma unroll
      for (int ki = 0; ki < 4; ki++)
#pragma unroll
        for (int qi = 0; qi < 4; qi++)
          S[ki][qi] =
              __builtin_amdgcn_mfma_f32_16x16x32_bf16(kf[ki], qf[qi][ks], S[ki][qi], 0, 0, 0);
    }

    const int kvb = t * 64;
#pragma unroll
    for (int qi = 0; qi < 4; qi++) {
      const int q = q0 + wq * 64 + qi * 16 + lr;
      float ls = 0.f;
#pragma unroll
      for (int ki = 0; ki < 4; ki++) {
        union { bf16 h[4]; uint2 u; } pk;
#pragma unroll
        for (int j = 0; j < 4; j++) {
          int kv = kvb + ki * 16 + kg * 4 + j;
          float e = (kv <= q) ? exp2f(S[ki][qi][j]) : 0.f;
          ls += e;
          pk.h[j] = (bf16)e;
        }
        *(uint2*)(Pw + (qi * 16 + lr) * 144 + (ki * 16 + kg * 4) * 2) = pk.u;
      }
      ls += __shfl_xor(ls, 16);
      ls += __shfl_xor(ls, 32);
      lrun[qi] += ls;
    }
    LGK0();
    SB0();

    const char* Vb = L + 32768 + cur * 8192;
#pragma unroll
    for (int ks = 0; ks < 2; ks++) {
      bf16x8 pf[4], vf[4];
#pragma unroll
      for (int qi = 0; qi < 4; qi++)
        pf[qi] = *(const bf16x8*)(Pw + (qi * 16 + lr) * 144 + ks * 64 + kg * 16);
#pragma unroll
      for (int di = 0; di < 4; di++) {
        int d = di * 16 + lr;
        vf[di] = *(const bf16x8*)(Vb + d * 128 + ((ks * 64 + kg * 16) ^ ((d & 7) << 4)));
      }
#pragma unroll
      for (int qi = 0; qi < 4; qi++)
#pragma unroll
        for (int di = 0; di < 4; di++)
          O[qi][di] =
              __builtin_amdgcn_mfma_f32_16x16x32_bf16(pf[qi], vf[di], O[qi][di], 0, 0, 0);
    }
    __syncthreads();
    cur ^= 1;
  }

#pragma unroll
  for (int qi = 0; qi < 4; qi++) {
#pragma unroll
    for (int j = 0; j < 4; j++) {
      float lv = __shfl(lrun[qi], kg * 4 + j);
      float inv = 1.f / lv;
      long grow = bq + q0 + wq * 64 + qi * 16 + kg * 4 + j;
#pragma unroll
      for (int di = 0; di < 4; di++)
        out[grow * kE + hh * 64 + di * 16 + lr] = (bf16)(O[qi][di][j] * inv);
    }
  }
}

// ---------------- V section of qkv [M,3E] -> vtG [B*H][64 d][1024 t], pre-swizzled
__global__ void vtrans_k(const bf16* __restrict__ qkv, bf16* __restrict__ vt) {
  __shared__ bf16 tbuf[32][33];
  int z = blockIdx.z;
  int b = z >> 4, h = z & 15;
  int t0 = blockIdx.x * 32, s0 = blockIdx.y * 32;
  int tx = threadIdx.x, ty = threadIdx.y;
#pragma unroll
  for (int i = 0; i < 32; i += 8)
    tbuf[ty + i][tx] = qkv[((long)b * kT + t0 + ty + i) * 3072 + 2048 + h * 64 + s0 + tx];
  __syncthreads();
#pragma unroll
  for (int i = 0; i < 32; i += 8) {
    int d = s0 + ty + i;
    int tt = t0 + tx;
    int g = (tt >> 3) & 7, e = tt & 7;
    long idx = ((long)z * 64 + d) * kT + (tt & ~63) + ((g ^ (d & 7)) << 3) + e;
    vt[idx] = tbuf[tx][ty + i];
  }
}

// ---------------- transpose + f32->bf16 convert (vectorized writes)
__global__ void tcvt_k(const float* __restrict__ in, bf16* __restrict__ out, int K, int N,
                       long in_zs, long out_zs) {
  __shared__ float t[64][33];
  long z = blockIdx.z;
  in += z * in_zs;
  out += z * out_zs;
  int n0 = blockIdx.x * 32, k0 = blockIdx.y * 64;
  int tid = threadIdx.y * 32 + threadIdx.x;
  int tx = threadIdx.x, ty = threadIdx.y;
#pragma unroll
  for (int i = 0; i < 8; i++) t[ty + i * 8][tx] = in[(long)(k0 + ty + i * 8) * N + n0 + tx];
  __syncthreads();
#pragma unroll
  for (int it = 0; it < 2; it++) {
    int q = it * 256 + tid;
    int r = q >> 4;
    int jj = q & 15;
    union { bf16 h[4]; uint2 u; } pk;
#pragma unroll
    for (int e = 0; e < 4; e++) pk.h[e] = (bf16)t[jj * 4 + e][r];
    *(uint2*)(out + (long)(n0 + r) * K + k0 + jj * 4) = pk.u;
  }
}

// ---------------- embedding
__global__ void embed_k(const int* __restrict__ toks, const float* __restrict__ te,
                        const float* __restrict__ pe, float* __restrict__ x) {
  int row = blockIdx.x, tid = threadIdx.x;
  int t = row & (kT - 1);
  long tok = toks[row];
  float4 a = ((const float4*)(te + tok * kE))[tid];
  float4 p = ((const float4*)(pe + (long)t * kE))[tid];
  float4 r{a.x + p.x, a.y + p.y, a.z + p.z, a.w + p.w};
  ((float4*)(x + (long)row * kE))[tid] = r;
}

// ---------------- LayerNorm (f32 in) -> bf16 out
__global__ void ln_k(const float* __restrict__ x, const float* __restrict__ g,
                     const float* __restrict__ b, bf16* __restrict__ h) {
  int row = blockIdx.x, tid = threadIdx.x, lane = tid & 63, w = tid >> 6;
  const float4 v = ((const float4*)(x + (long)row * kE))[tid];
  float s = v.x + v.y + v.z + v.w;
  float ss = v.x * v.x + v.y * v.y + v.z * v.z + v.w * v.w;
#pragma unroll
  for (int o = 32; o; o >>= 1) {
    s += __shfl_xor(s, o);
    ss += __shfl_xor(ss, o);
  }
  __shared__ float r1[4], r2[4];
  if (lane == 0) { r1[w] = s; r2[w] = ss; }
  __syncthreads();
  s = r1[0] + r1[1] + r1[2] + r1[3];
  ss = r2[0] + r2[1] + r2[2] + r2[3];
  float mean = s * (1.f / kE);
  float var = ss * (1.f / kE) - mean * mean;
  float rs = rsqrtf(var + 1e-5f);
  float4 gg = ((const float4*)g)[tid];
  float4 bb = ((const float4*)b)[tid];
  union { bf16 o[4]; uint2 u; } pk;
  pk.o[0] = (bf16)((v.x - mean) * rs * gg.x + bb.x);
  pk.o[1] = (bf16)((v.y - mean) * rs * gg.y + bb.y);
  pk.o[2] = (bf16)((v.z - mean) * rs * gg.z + bb.z);
  pk.o[3] = (bf16)((v.w - mean) * rs * gg.w + bb.w);
  ((uint2*)(h + (long)row * kE))[tid] = pk.u;
}

// ---------------- f32 -> bf16 cast
__global__ void cast_k(const float* __restrict__ x, bf16* __restrict__ o) {
  long i = (long)blockIdx.x * 256 + threadIdx.x;
  float4 v = ((const float4*)x)[i];
  union { bf16 b[4]; uint2 u; } pk;
  pk.b[0] = (bf16)v.x;
  pk.b[1] = (bf16)v.y;
  pk.b[2] = (bf16)v.z;
  pk.b[3] = (bf16)v.w;
  ((uint2*)o)[i] = pk.u;
}

extern "C" void kernel_launch(void* const* d_in, const int* in_sizes, int n_in,
                              void* d_out, int out_size, void* d_ws, size_t ws_size,
                              hipStream_t stream) {
  const int* toks = (const int*)d_in[0];
  const float* te = (const float*)d_in[1];
  const float* pe = (const float*)d_in[2];
  const float* Wq = (const float*)d_in[3];
  const float* Wk = (const float*)d_in[4];
  const float* Wv = (const float*)d_in[5];
  const float* Wo = (const float*)d_in[6];
  const float* g1 = (const float*)d_in[7];
  const float* be1 = (const float*)d_in[8];
  const float* W1 = (const float*)d_in[9];
  const float* bb1 = (const float*)d_in[10];
  const float* W2 = (const float*)d_in[11];
  const float* bb2 = (const float*)d_in[12];
  const float* g2 = (const float*)d_in[13];
  const float* be2 = (const float*)d_in[14];
  const float* lmw = (const float*)d_in[15];
  const float* lmb = (const float*)d_in[16];

  hipFuncSetAttribute(reinterpret_cast<const void*>(&gemm256_k<EPI_BF16>),
                      hipFuncAttributeMaxDynamicSharedMemorySize, 131072);
  hipFuncSetAttribute(reinterpret_cast<const void*>(&gemm256_k<EPI_BF16_BIAS_RELU>),
                      hipFuncAttributeMaxDynamicSharedMemorySize, 131072);
  hipFuncSetAttribute(reinterpret_cast<const void*>(&gemm256_k<EPI_F32_BIAS>),
                      hipFuncAttributeMaxDynamicSharedMemorySize, 131072);
  hipFuncSetAttribute(reinterpret_cast<const void*>(&ring128_k<EPI_F32_RES>),
                      hipFuncAttributeMaxDynamicSharedMemorySize, 65536);
  hipFuncSetAttribute(reinterpret_cast<const void*>(&fa_k),
                      hipFuncAttributeMaxDynamicSharedMemorySize, 67584);

  char* ws = (char*)d_ws;
  size_t off = 0;
  auto alloc = [&](size_t bytes) -> char* {
    char* p = ws + off;
    off += (bytes + 255) & ~(size_t)255;
    return p;
  };
  bf16* WqkvT = (bf16*)alloc((size_t)kL * 3 * kE * kE * 2);
  bf16* WoT = (bf16*)alloc((size_t)kL * kE * kE * 2);
  bf16* W1T = (bf16*)alloc((size_t)kL * kE * kFF * 2);
  bf16* W2T = (bf16*)alloc((size_t)kL * kE * kFF * 2);
  bf16* lmT = (bf16*)alloc((size_t)kV * kE * 2);
  float* x = (float*)alloc((size_t)kM * kE * 4);
  bf16* h = (bf16*)alloc((size_t)kM * kE * 2);
  bf16* qkv = (bf16*)alloc((size_t)kM * 3 * kE * 2);
  bf16* at = (bf16*)alloc((size_t)kM * kE * 2);
  bf16* vtG = (bf16*)alloc((size_t)kB * kH * 64 * kT * 2);

  bf16* mid = (bf16*)d_out;  // scratch; LM head overwrites d_out at the end

  const long EE = (long)kE * kE;
  dim3 tb(32, 8);
  tcvt_k<<<dim3(kE / 32, kE / 64, kL), tb, 0, stream>>>(Wq, WqkvT, kE, kE, EE, 3 * EE);
  tcvt_k<<<dim3(kE / 32, kE / 64, kL), tb, 0, stream>>>(Wk, WqkvT + EE, kE, kE, EE, 3 * EE);
  tcvt_k<<<dim3(kE / 32, kE / 64, kL), tb, 0, stream>>>(Wv, WqkvT + 2 * EE, kE, kE, EE, 3 * EE);
  tcvt_k<<<dim3(kE / 32, kE / 64, kL), tb, 0, stream>>>(Wo, WoT, kE, kE, EE, EE);
  tcvt_k<<<dim3(kFF / 32, kE / 64, kL), tb, 0, stream>>>(W1, W1T, kE, kFF, 4 * EE, 4 * EE);
  tcvt_k<<<dim3(kE / 32, kFF / 64, kL), tb, 0, stream>>>(W2, W2T, kFF, kE, 4 * EE, 4 * EE);
  tcvt_k<<<dim3(kV / 32, kE / 64, 1), tb, 0, stream>>>(lmw, lmT, kE, kV, 0, 0);

  embed_k<<<kM, 256, 0, stream>>>(toks, te, pe, x);

  for (int l = 0; l < kL; l++) {
    ln_k<<<kM, 256, 0, stream>>>(x, g1 + l * kE, be1 + l * kE, h);
    gemm256_k<EPI_BF16><<<dim3(3 * kE / 256, kM / 256), 512, 131072, stream>>>(
        h, WqkvT + (size_t)l * 3 * EE, qkv, nullptr, nullptr, kE, kE, kE, 3 * kE);
    vtrans_k<<<dim3(kT / 32, kHS / 32, kB * kH), tb, 0, stream>>>(qkv, vtG);
    fa_k<<<dim3(kB * kH, 8), 128, 67584, stream>>>(qkv, vtG, at);
    ring128_k<EPI_F32_RES><<<dim3(kE / 128, kM / 128), 256, 65536, stream>>>(
        at, WoT + (size_t)l * EE, x, nullptr, x, kE, kE, kE, kE);
    ln_k<<<kM, 256, 0, stream>>>(x, g2 + l * kE, be2 + l * kE, h);
    gemm256_k<EPI_BF16_BIAS_RELU><<<dim3(kFF / 256, kM / 256), 512, 131072, stream>>>(
        h, W1T + (size_t)l * (size_t)kFF * kE, mid, bb1 + l * kFF, nullptr, kE, kE, kE, kFF);
    ring128_k<EPI_F32_RES><<<dim3(kE / 128, kM / 128), 256, 65536, stream>>>(
        mid, W2T + (size_t)l * (size_t)kE * kFF, x, bb2 + l * kE, x, kFF, kFF, kFF, kE);
  }
  cast_k<<<kM * kE / 1024, 256, 0, stream>>>(x, h);
  gemm256_k<EPI_F32_BIAS><<<dim3(kV / 256, kM / 256), 512, 131072, stream>>>(
      h, lmT, d_out, lmb, nullptr, kE, kE, kE, kV);
}

// Round 14
// 1965.854 us; speedup vs baseline: 1.0266x; 1.0258x over previous
//
#include <hip/hip_runtime.h>
#include <cstdint>
#include <cstddef>

typedef __bf16 bf16;
typedef __attribute__((ext_vector_type(8))) __bf16 bf16x8;
typedef __attribute__((ext_vector_type(4))) float f32x4;

constexpr int kV = 32000, kE = 1024, kL = 6, kH = 16, kB = 4, kT = 1024;
constexpr int kHS = 64, kFF = 4096;
constexpr int kM = kB * kT;              // 4096 token rows
constexpr float kScale = 0.03125f;       // E^-0.5

typedef __attribute__((address_space(1))) void gv_t;
typedef __attribute__((address_space(3))) void lv_t;

__device__ inline void gload_lds16(const void* g, void* l) {
  __builtin_amdgcn_global_load_lds((gv_t*)g, (lv_t*)l, 16, 0, 0);
}

#define SB0() __builtin_amdgcn_sched_barrier(0)
#define LGK0() asm volatile("s_waitcnt lgkmcnt(0)" ::: "memory")

enum { EPI_BF16 = 0, EPI_BF16_BIAS_RELU = 1, EPI_F32 = 2, EPI_F32_RES = 3, EPI_F32_BIAS = 4 };

__device__ inline void xcd_swz(int& bx, int& by) {
  int gx = gridDim.x, gy = gridDim.y;
  int nxy = gx * gy;
  int orig = by * gx + bx;
  int q = nxy >> 3, r = nxy & 7, xcd = orig & 7, idx = orig >> 3;
  int logical = (xcd < r ? xcd * (q + 1) : r * (q + 1) + (xcd - r) * q) + idx;
  bx = logical / gy;
  by = logical % gy;
}

// ================= 256x256 4-slice ring GEMM (verified R8) =================
template <int EPI>
__global__ __launch_bounds__(512, 2) void gemm256_k(
    const bf16* __restrict__ Ag, const bf16* __restrict__ Bg, void* Cg,
    const float* __restrict__ bias, const float* __restrict__ resid,
    int K, long lda, long ldb, long ldc) {
  extern __shared__ bf16 lds[];
  constexpr int SL = 8192;
  bf16* As = lds;
  bf16* Bs = lds + 4 * SL;

  const int tid = threadIdx.x, lane = tid & 63, w = tid >> 6;
  int bx = blockIdx.x, by = blockIdx.y;
  xcd_swz(bx, by);
  const long tm = (long)by * 256, tn = (long)bx * 256;
  const int wr = w >> 2, wc = w & 3;
  const int lr = lane & 15, kg = lane >> 4;

  const int p0 = tid, p1 = 512 + tid;
  const int r0 = p0 >> 2, ls0 = (p0 & 3) ^ ((r0 >> 1) & 3);
  const int r1 = p1 >> 2, ls1 = (p1 & 3) ^ ((r1 >> 1) & 3);
  const bf16* a0 = Ag + (tm + r0) * lda + ls0 * 8;
  const bf16* a1 = Ag + (tm + r1) * lda + ls1 * 8;
  const bf16* b0 = Bg + (tn + r0) * ldb + ls0 * 8;
  const bf16* b1 = Bg + (tn + r1) * ldb + ls1 * 8;
  const int wb = w * 1024;

  auto stage = [&](int s) {
    const int slot = s & 3;
    const long k0 = (long)s * 32;
    char* Ab = (char*)As + slot * (SL * 2);
    char* Bb = (char*)Bs + slot * (SL * 2);
    gload_lds16(a0 + k0, Ab + wb);
    gload_lds16(a1 + k0, Ab + 8192 + wb);
    gload_lds16(b0 + k0, Bb + wb);
    gload_lds16(b1 + k0, Bb + 8192 + wb);
  };

  int aoff[8], boff[4];
#pragma unroll
  for (int mi = 0; mi < 8; mi++) {
    int ar = wr * 128 + mi * 16 + lr;
    aoff[mi] = ar * 64 + ((kg ^ ((ar >> 1) & 3)) << 4);
  }
#pragma unroll
  for (int ni = 0; ni < 4; ni++) {
    int br = wc * 64 + ni * 16 + lr;
    boff[ni] = br * 64 + ((kg ^ ((br >> 1) & 3)) << 4);
  }

  f32x4 acc[8][4] = {};
  stage(0);
  stage(1);
  stage(2);
  const int NS = K >> 5;
  for (int s = 0; s < NS; s++) {
    SB0();
    if (s <= NS - 3)
      asm volatile("s_waitcnt vmcnt(8)" ::: "memory");
    else if (s == NS - 2)
      asm volatile("s_waitcnt vmcnt(4)" ::: "memory");
    else
      asm volatile("s_waitcnt vmcnt(0)" ::: "memory");
    __builtin_amdgcn_s_barrier();
    SB0();
    if (s + 3 < NS) stage(s + 3);
    const char* Ab = (const char*)As + (s & 3) * (SL * 2);
    const char* Bb = (const char*)Bs + (s & 3) * (SL * 2);
    bf16x8 af[8], bfr[4];
#pragma unroll
    for (int mi = 0; mi < 8; mi++) af[mi] = *(const bf16x8*)(Ab + aoff[mi]);
#pragma unroll
    for (int ni = 0; ni < 4; ni++) bfr[ni] = *(const bf16x8*)(Bb + boff[ni]);
    __builtin_amdgcn_s_setprio(1);
#pragma unroll
    for (int mi = 0; mi < 8; mi++)
#pragma unroll
      for (int ni = 0; ni < 4; ni++)
        acc[mi][ni] =
            __builtin_amdgcn_mfma_f32_16x16x32_bf16(af[mi], bfr[ni], acc[mi][ni], 0, 0, 0);
    __builtin_amdgcn_s_setprio(0);
  }

#pragma unroll
  for (int mi = 0; mi < 8; mi++) {
#pragma unroll
    for (int ni = 0; ni < 4; ni++) {
      const long rr = tm + wr * 128 + mi * 16 + kg * 4;
      const long cc = tn + wc * 64 + ni * 16 + lr;
      float bi = 0.f;
      if constexpr (EPI == EPI_BF16_BIAS_RELU || EPI == EPI_F32_BIAS) bi = bias[cc];
      if constexpr (EPI == EPI_F32_RES) bi = bias ? bias[cc] : 0.f;
#pragma unroll
      for (int j = 0; j < 4; j++) {
        long off = (rr + j) * ldc + cc;
        float val = acc[mi][ni][j];
        if constexpr (EPI == EPI_BF16)
          ((bf16*)Cg)[off] = (bf16)val;
        else if constexpr (EPI == EPI_BF16_BIAS_RELU)
          ((bf16*)Cg)[off] = (bf16)fmaxf(val + bi, 0.f);
        else if constexpr (EPI == EPI_F32)
          ((float*)Cg)[off] = val;
        else if constexpr (EPI == EPI_F32_RES)
          ((float*)Cg)[off] = resid[off] + val + bi;
        else
          ((float*)Cg)[off] = val + bi;
      }
    }
  }
}

// ================= 128x128 4-slice ring GEMM (verified R8) =================
template <int EPI>
__global__ __launch_bounds__(256, 2) void ring128_k(
    const bf16* __restrict__ Ag, const bf16* __restrict__ Bg, void* Cg,
    const float* __restrict__ bias, const float* __restrict__ resid,
    int K, long lda, long ldb, long ldc) {
  extern __shared__ bf16 lds[];
  char* Lb = (char*)lds;  // 4 slices x (A 8192B + B 8192B)
  const int tid = threadIdx.x, lane = tid & 63, w = tid >> 6;
  int bx = blockIdx.x, by = blockIdx.y;
  xcd_swz(bx, by);
  const long tm = (long)by * 128, tn = (long)bx * 128;
  const int wr = w >> 1, wc = w & 1;  // wave grid 2 x 2
  const int lr = lane & 15, kg = lane >> 4;

  const int r0 = tid >> 2, g0 = (tid & 3) ^ ((r0 >> 1) & 3);
  const int r1 = (256 + tid) >> 2, g1 = ((256 + tid) & 3) ^ ((r1 >> 1) & 3);
  const bf16* a0 = Ag + (tm + r0) * lda + g0 * 8;
  const bf16* a1 = Ag + (tm + r1) * lda + g1 * 8;
  const bf16* b0 = Bg + (tn + r0) * ldb + g0 * 8;
  const bf16* b1 = Bg + (tn + r1) * ldb + g1 * 8;
  const int wb = w * 1024;

  auto stage = [&](int s) {
    const int slot = s & 3;
    const long k0 = (long)s * 32;
    char* Ab = Lb + slot * 16384;
    char* Bb = Ab + 8192;
    gload_lds16(a0 + k0, Ab + wb);
    gload_lds16(a1 + k0, Ab + 4096 + wb);
    gload_lds16(b0 + k0, Bb + wb);
    gload_lds16(b1 + k0, Bb + 4096 + wb);
  };

  int aoff[4], boff[4];
#pragma unroll
  for (int mi = 0; mi < 4; mi++) {
    int ar = wr * 64 + mi * 16 + lr;
    aoff[mi] = ar * 64 + ((kg ^ ((ar >> 1) & 3)) << 4);
  }
#pragma unroll
  for (int ni = 0; ni < 4; ni++) {
    int br = wc * 64 + ni * 16 + lr;
    boff[ni] = br * 64 + ((kg ^ ((br >> 1) & 3)) << 4);
  }

  f32x4 acc[4][4] = {};
  stage(0);
  stage(1);
  stage(2);
  const int NS = K >> 5;
  for (int s = 0; s < NS; s++) {
    SB0();
    if (s <= NS - 3)
      asm volatile("s_waitcnt vmcnt(8)" ::: "memory");
    else if (s == NS - 2)
      asm volatile("s_waitcnt vmcnt(4)" ::: "memory");
    else
      asm volatile("s_waitcnt vmcnt(0)" ::: "memory");
    __builtin_amdgcn_s_barrier();
    SB0();
    if (s + 3 < NS) stage(s + 3);
    const char* Ab = Lb + (s & 3) * 16384;
    const char* Bb = Ab + 8192;
    bf16x8 af[4], bfr[4];
#pragma unroll
    for (int mi = 0; mi < 4; mi++) af[mi] = *(const bf16x8*)(Ab + aoff[mi]);
#pragma unroll
    for (int ni = 0; ni < 4; ni++) bfr[ni] = *(const bf16x8*)(Bb + boff[ni]);
    __builtin_amdgcn_s_setprio(1);
#pragma unroll
    for (int mi = 0; mi < 4; mi++)
#pragma unroll
      for (int ni = 0; ni < 4; ni++)
        acc[mi][ni] =
            __builtin_amdgcn_mfma_f32_16x16x32_bf16(af[mi], bfr[ni], acc[mi][ni], 0, 0, 0);
    __builtin_amdgcn_s_setprio(0);
  }

#pragma unroll
  for (int mi = 0; mi < 4; mi++) {
#pragma unroll
    for (int ni = 0; ni < 4; ni++) {
      const long rr = tm + wr * 64 + mi * 16 + kg * 4;
      const long cc = tn + wc * 64 + ni * 16 + lr;
      float bi = 0.f;
      if constexpr (EPI == EPI_BF16_BIAS_RELU || EPI == EPI_F32_BIAS) bi = bias[cc];
      if constexpr (EPI == EPI_F32_RES) bi = bias ? bias[cc] : 0.f;
#pragma unroll
      for (int j = 0; j < 4; j++) {
        long off = (rr + j) * ldc + cc;
        float val = acc[mi][ni][j];
        if constexpr (EPI == EPI_BF16)
          ((bf16*)Cg)[off] = (bf16)val;
        else if constexpr (EPI == EPI_BF16_BIAS_RELU)
          ((bf16*)Cg)[off] = (bf16)fmaxf(val + bi, 0.f);
        else if constexpr (EPI == EPI_F32)
          ((float*)Cg)[off] = val;
        else if constexpr (EPI == EPI_F32_RES)
          ((float*)Cg)[off] = resid[off] + val + bi;
        else
          ((float*)Cg)[off] = val + bi;
      }
    }
  }
}

// ================= fused flash attention v2 (R8: __expf + kScale) =================
__global__ __launch_bounds__(128) void fa_k(const bf16* __restrict__ qkv,
                                            const bf16* __restrict__ vtG,
                                            bf16* __restrict__ out) {
  extern __shared__ bf16 lds[];
  char* L = (char*)lds;
  const int tid = threadIdx.x, lane = tid & 63, wq = tid >> 6;
  const int lr = lane & 15, kg = lane >> 4;
  const int bh = blockIdx.x, z = blockIdx.y;
  const int b = bh >> 4, hh = bh & 15;
  const long bq = (long)b * kT;
  const int qt = z < 4 ? z : 11 - z;
  const int q0 = qt * 128;
  const bf16* qbase = qkv + (bq + q0) * 3072 + hh * 64;
  const bf16* vbase = vtG + (long)bh * 64 * kT;

#pragma unroll
  for (int i = 0; i < 8; i++) {
    int p = i * 128 + tid;
    int row = p >> 3, s = p & 7;
    gload_lds16(qbase + (long)row * 3072 + ((s ^ (row & 7)) * 8),
                L + (i * 128 + (tid & ~63)) * 16);
  }
  auto stageKV = [&](int buf, int t) {
    const bf16* kb = qkv + (bq + t * 64) * 3072 + 1024 + hh * 64;
    const bf16* vb = vbase + t * 64;
#pragma unroll
    for (int i = 0; i < 4; i++) {
      int p = i * 128 + tid;
      int key = p >> 3, s = p & 7;
      gload_lds16(kb + (long)key * 3072 + ((s ^ (key & 7)) * 8),
                  L + 16384 + buf * 8192 + (i * 128 + (tid & ~63)) * 16);
    }
#pragma unroll
    for (int i = 0; i < 4; i++) {
      int p = i * 128 + tid;
      int key = p >> 3, s = p & 7;
      gload_lds16(vb + (long)key * kT + s * 8,
                  L + 32768 + buf * 8192 + (i * 128 + (tid & ~63)) * 16);
    }
  };
  stageKV(0, 0);
  __syncthreads();

  // Q fragments pre-scaled by 1/32 (exact: power of 2); softmax via __expf
  bf16x8 qf[4][2];
#pragma unroll
  for (int qi = 0; qi < 4; qi++)
#pragma unroll
    for (int ks = 0; ks < 2; ks++) {
      int qr = wq * 64 + qi * 16 + lr;
      bf16x8 v = *(const bf16x8*)(L + qr * 128 + ((ks * 64 + kg * 16) ^ ((qr & 7) << 4)));
#pragma unroll
      for (int e = 0; e < 8; e++) v[e] = (bf16)((float)v[e] * kScale);
      qf[qi][ks] = v;
    }

  f32x4 O[4][4] = {};
  float lrun[4] = {0.f, 0.f, 0.f, 0.f};
  char* Pw = L + 49152 + wq * 9216;

  const int nt = 2 * qt + 2;
  int cur = 0;
  for (int t = 0; t < nt; t++) {
    if (t + 1 < nt) stageKV(cur ^ 1, t + 1);

    const char* Kb = L + 16384 + cur * 8192;
    f32x4 S[4][4] = {};
#pragma unroll
    for (int ks = 0; ks < 2; ks++) {
      bf16x8 kf[4];
#pragma unroll
      for (int ki = 0; ki < 4; ki++) {
        int key = ki * 16 + lr;
        kf[ki] = *(const bf16x8*)(Kb + key * 128 + ((ks * 64 + kg * 16) ^ ((key & 7) << 4)));
      }
#pragma unroll
      for (int ki = 0; ki < 4; ki++)
#pragma unroll
        for (int qi = 0; qi < 4; qi++)
          S[ki][qi] =
              __builtin_amdgcn_mfma_f32_16x16x32_bf16(kf[ki], qf[qi][ks], S[ki][qi], 0, 0, 0);
    }

    const int kvb = t * 64;
#pragma unroll
    for (int qi = 0; qi < 4; qi++) {
      const int q = q0 + wq * 64 + qi * 16 + lr;
      float ls = 0.f;
#pragma unroll
      for (int ki = 0; ki < 4; ki++) {
        union { bf16 h[4]; uint2 u; } pk;
#pragma unroll
        for (int j = 0; j < 4; j++) {
          int kv = kvb + ki * 16 + kg * 4 + j;
          float e = (kv <= q) ? __expf(S[ki][qi][j]) : 0.f;
          ls += e;
          pk.h[j] = (bf16)e;
        }
        *(uint2*)(Pw + (qi * 16 + lr) * 144 + (ki * 16 + kg * 4) * 2) = pk.u;
      }
      ls += __shfl_xor(ls, 16);
      ls += __shfl_xor(ls, 32);
      lrun[qi] += ls;
    }
    LGK0();
    SB0();

    const char* Vb = L + 32768 + cur * 8192;
#pragma unroll
    for (int ks = 0; ks < 2; ks++) {
      bf16x8 pf[4], vf[4];
#pragma unroll
      for (int qi = 0; qi < 4; qi++)
        pf[qi] = *(const bf16x8*)(Pw + (qi * 16 + lr) * 144 + ks * 64 + kg * 16);
#pragma unroll
      for (int di = 0; di < 4; di++) {
        int d = di * 16 + lr;
        vf[di] = *(const bf16x8*)(Vb + d * 128 + ((ks * 64 + kg * 16) ^ ((d & 7) << 4)));
      }
#pragma unroll
      for (int qi = 0; qi < 4; qi++)
#pragma unroll
        for (int di = 0; di < 4; di++)
          O[qi][di] =
              __builtin_amdgcn_mfma_f32_16x16x32_bf16(pf[qi], vf[di], O[qi][di], 0, 0, 0);
    }
    __syncthreads();
    cur ^= 1;
  }

#pragma unroll
  for (int qi = 0; qi < 4; qi++) {
#pragma unroll
    for (int j = 0; j < 4; j++) {
      float lv = __shfl(lrun[qi], kg * 4 + j);
      float inv = 1.f / lv;
      long grow = bq + q0 + wq * 64 + qi * 16 + kg * 4 + j;
#pragma unroll
      for (int di = 0; di < 4; di++)
        out[grow * kE + hh * 64 + di * 16 + lr] = (bf16)(O[qi][di][j] * inv);
    }
  }
}

// ---------------- V section of qkv [M,3E] -> vtG [B*H][64 d][1024 t], pre-swizzled
__global__ void vtrans_k(const bf16* __restrict__ qkv, bf16* __restrict__ vt) {
  __shared__ bf16 tbuf[32][33];
  int z = blockIdx.z;
  int b = z >> 4, h = z & 15;
  int t0 = blockIdx.x * 32, s0 = blockIdx.y * 32;
  int tx = threadIdx.x, ty = threadIdx.y;
#pragma unroll
  for (int i = 0; i < 32; i += 8)
    tbuf[ty + i][tx] = qkv[((long)b * kT + t0 + ty + i) * 3072 + 2048 + h * 64 + s0 + tx];
  __syncthreads();
#pragma unroll
  for (int i = 0; i < 32; i += 8) {
    int d = s0 + ty + i;
    int tt = t0 + tx;
    int g = (tt >> 3) & 7, e = tt & 7;
    long idx = ((long)z * 64 + d) * kT + (tt & ~63) + ((g ^ (d & 7)) << 3) + e;
    vt[idx] = tbuf[tx][ty + i];
  }
}

// ---------------- transpose + f32->bf16 convert (R8 32x32 version)
__global__ void tcvt_k(const float* __restrict__ in, bf16* __restrict__ out, int K, int N,
                       long in_zs, long out_zs) {
  __shared__ float t[32][33];
  long z = blockIdx.z;
  in += z * in_zs;
  out += z * out_zs;
  int n0 = blockIdx.x * 32, k0 = blockIdx.y * 32;
  int tx = threadIdx.x, ty = threadIdx.y;
#pragma unroll
  for (int i = 0; i < 32; i += 8) t[ty + i][tx] = in[(long)(k0 + ty + i) * N + n0 + tx];
  __syncthreads();
#pragma unroll
  for (int i = 0; i < 32; i += 8)
    out[(long)(n0 + ty + i) * K + k0 + tx] = (bf16)t[tx][ty + i];
}

// ---------------- embedding
__global__ void embed_k(const int* __restrict__ toks, const float* __restrict__ te,
                        const float* __restrict__ pe, float* __restrict__ x) {
  int row = blockIdx.x, tid = threadIdx.x;
  int t = row & (kT - 1);
  long tok = toks[row];
  float4 a = ((const float4*)(te + tok * kE))[tid];
  float4 p = ((const float4*)(pe + (long)t * kE))[tid];
  float4 r{a.x + p.x, a.y + p.y, a.z + p.z, a.w + p.w};
  ((float4*)(x + (long)row * kE))[tid] = r;
}

// ---------------- LayerNorm (f32 in) -> bf16 out
__global__ void ln_k(const float* __restrict__ x, const float* __restrict__ g,
                     const float* __restrict__ b, bf16* __restrict__ h) {
  int row = blockIdx.x, tid = threadIdx.x, lane = tid & 63, w = tid >> 6;
  const float4 v = ((const float4*)(x + (long)row * kE))[tid];
  float s = v.x + v.y + v.z + v.w;
  float ss = v.x * v.x + v.y * v.y + v.z * v.z + v.w * v.w;
#pragma unroll
  for (int o = 32; o; o >>= 1) {
    s += __shfl_xor(s, o);
    ss += __shfl_xor(ss, o);
  }
  __shared__ float r1[4], r2[4];
  if (lane == 0) { r1[w] = s; r2[w] = ss; }
  __syncthreads();
  s = r1[0] + r1[1] + r1[2] + r1[3];
  ss = r2[0] + r2[1] + r2[2] + r2[3];
  float mean = s * (1.f / kE);
  float var = ss * (1.f / kE) - mean * mean;
  float rs = rsqrtf(var + 1e-5f);
  float4 gg = ((const float4*)g)[tid];
  float4 bb = ((const float4*)b)[tid];
  union { bf16 o[4]; uint2 u; } pk;
  pk.o[0] = (bf16)((v.x - mean) * rs * gg.x + bb.x);
  pk.o[1] = (bf16)((v.y - mean) * rs * gg.y + bb.y);
  pk.o[2] = (bf16)((v.z - mean) * rs * gg.z + bb.z);
  pk.o[3] = (bf16)((v.w - mean) * rs * gg.w + bb.w);
  ((uint2*)(h + (long)row * kE))[tid] = pk.u;
}

// ---------------- f32 -> bf16 cast
__global__ void cast_k(const float* __restrict__ x, bf16* __restrict__ o) {
  long i = (long)blockIdx.x * 256 + threadIdx.x;
  float4 v = ((const float4*)x)[i];
  union { bf16 b[4]; uint2 u; } pk;
  pk.b[0] = (bf16)v.x;
  pk.b[1] = (bf16)v.y;
  pk.b[2] = (bf16)v.z;
  pk.b[3] = (bf16)v.w;
  ((uint2*)o)[i] = pk.u;
}

extern "C" void kernel_launch(void* const* d_in, const int* in_sizes, int n_in,
                              void* d_out, int out_size, void* d_ws, size_t ws_size,
                              hipStream_t stream) {
  const int* toks = (const int*)d_in[0];
  const float* te = (const float*)d_in[1];
  const float* pe = (const float*)d_in[2];
  const float* Wq = (const float*)d_in[3];
  const float* Wk = (const float*)d_in[4];
  const float* Wv = (const float*)d_in[5];
  const float* Wo = (const float*)d_in[6];
  const float* g1 = (const float*)d_in[7];
  const float* be1 = (const float*)d_in[8];
  const float* W1 = (const float*)d_in[9];
  const float* bb1 = (const float*)d_in[10];
  const float* W2 = (const float*)d_in[11];
  const float* bb2 = (const float*)d_in[12];
  const float* g2 = (const float*)d_in[13];
  const float* be2 = (const float*)d_in[14];
  const float* lmw = (const float*)d_in[15];
  const float* lmb = (const float*)d_in[16];

  hipFuncSetAttribute(reinterpret_cast<const void*>(&gemm256_k<EPI_BF16>),
                      hipFuncAttributeMaxDynamicSharedMemorySize, 131072);
  hipFuncSetAttribute(reinterpret_cast<const void*>(&gemm256_k<EPI_BF16_BIAS_RELU>),
                      hipFuncAttributeMaxDynamicSharedMemorySize, 131072);
  hipFuncSetAttribute(reinterpret_cast<const void*>(&gemm256_k<EPI_F32_BIAS>),
                      hipFuncAttributeMaxDynamicSharedMemorySize, 131072);
  hipFuncSetAttribute(reinterpret_cast<const void*>(&ring128_k<EPI_F32_RES>),
                      hipFuncAttributeMaxDynamicSharedMemorySize, 65536);
  hipFuncSetAttribute(reinterpret_cast<const void*>(&fa_k),
                      hipFuncAttributeMaxDynamicSharedMemorySize, 67584);

  char* ws = (char*)d_ws;
  size_t off = 0;
  auto alloc = [&](size_t bytes) -> char* {
    char* p = ws + off;
    off += (bytes + 255) & ~(size_t)255;
    return p;
  };
  bf16* WqkvT = (bf16*)alloc((size_t)kL * 3 * kE * kE * 2);
  bf16* WoT = (bf16*)alloc((size_t)kL * kE * kE * 2);
  bf16* W1T = (bf16*)alloc((size_t)kL * kE * kFF * 2);
  bf16* W2T = (bf16*)alloc((size_t)kL * kE * kFF * 2);
  bf16* lmT = (bf16*)alloc((size_t)kV * kE * 2);
  float* x = (float*)alloc((size_t)kM * kE * 4);
  bf16* h = (bf16*)alloc((size_t)kM * kE * 2);
  bf16* qkv = (bf16*)alloc((size_t)kM * 3 * kE * 2);
  bf16* at = (bf16*)alloc((size_t)kM * kE * 2);
  bf16* vtG = (bf16*)alloc((size_t)kB * kH * 64 * kT * 2);

  bf16* mid = (bf16*)d_out;  // scratch; LM head overwrites d_out at the end

  const long EE = (long)kE * kE;
  dim3 tb(32, 8);
  tcvt_k<<<dim3(kE / 32, kE / 32, kL), tb, 0, stream>>>(Wq, WqkvT, kE, kE, EE, 3 * EE);
  tcvt_k<<<dim3(kE / 32, kE / 32, kL), tb, 0, stream>>>(Wk, WqkvT + EE, kE, kE, EE, 3 * EE);
  tcvt_k<<<dim3(kE / 32, kE / 32, kL), tb, 0, stream>>>(Wv, WqkvT + 2 * EE, kE, kE, EE, 3 * EE);
  tcvt_k<<<dim3(kE / 32, kE / 32, kL), tb, 0, stream>>>(Wo, WoT, kE, kE, EE, EE);
  tcvt_k<<<dim3(kFF / 32, kE / 32, kL), tb, 0, stream>>>(W1, W1T, kE, kFF, 4 * EE, 4 * EE);
  tcvt_k<<<dim3(kE / 32, kFF / 32, kL), tb, 0, stream>>>(W2, W2T, kFF, kE, 4 * EE, 4 * EE);
  tcvt_k<<<dim3(kV / 32, kE / 32, 1), tb, 0, stream>>>(lmw, lmT, kE, kV, 0, 0);

  embed_k<<<kM, 256, 0, stream>>>(toks, te, pe, x);

  for (int l = 0; l < kL; l++) {
    ln_k<<<kM, 256, 0, stream>>>(x, g1 + l * kE, be1 + l * kE, h);
    gemm256_k<EPI_BF16><<<dim3(3 * kE / 256, kM / 256), 512, 131072, stream>>>(
        h, WqkvT + (size_t)l * 3 * EE, qkv, nullptr, nullptr, kE, kE, kE, 3 * kE);
    vtrans_k<<<dim3(kT / 32, kHS / 32, kB * kH), tb, 0, stream>>>(qkv, vtG);
    fa_k<<<dim3(kB * kH, 8), 128, 67584, stream>>>(qkv, vtG, at);
    ring128_k<EPI_F32_RES><<<dim3(kE / 128, kM / 128), 256, 65536, stream>>>(
        at, WoT + (size_t)l * EE, x, nullptr, x, kE, kE, kE, kE);
    ln_k<<<kM, 256, 0, stream>>>(x, g2 + l * kE, be2 + l * kE, h);
    gemm256_k<EPI_BF16_BIAS_RELU><<<dim3(kFF / 256, kM / 256), 512, 131072, stream>>>(
        h, W1T + (size_t)l * (size_t)kFF * kE, mid, bb1 + l * kFF, nullptr, kE, kE, kE, kFF);
    ring128_k<EPI_F32_RES><<<dim3(kE / 128, kM / 128), 256, 65536, stream>>>(
        mid, W2T + (size_t)l * (size_t)kE * kFF, x, bb2 + l * kE, x, kFF, kFF, kFF, kE);
  }
  cast_k<<<kM * kE / 1024, 256, 0, stream>>>(x, h);
  gemm256_k<EPI_F32_BIAS><<<dim3(kV / 256, kM / 256), 512, 131072, stream>>>(
      h, lmT, d_out, lmb, nullptr, kE, kE, kE, kV);
}